// Round 3
// baseline (622.702 us; speedup 1.0000x reference)
//
#include <hip/hip_runtime.h>

#define CC 128
#define NHEADS 8
#define DHD 16
#define LLONG 64
#define BLONG 512
#define LSHORT 1024
#define BSHORT 32

__device__ __forceinline__ float dot4(float4 a, float4 b, float acc) {
  acc = fmaf(a.x, b.x, acc); acc = fmaf(a.y, b.y, acc);
  acc = fmaf(a.z, b.z, acc); acc = fmaf(a.w, b.w, acc);
  return acc;
}
__device__ __forceinline__ float4 fma4(float p, float4 v, float4 o) {
  o.x = fmaf(p, v.x, o.x); o.y = fmaf(p, v.y, o.y);
  o.z = fmaf(p, v.z, o.z); o.w = fmaf(p, v.w, o.w);
  return o;
}
__device__ __forceinline__ float4 mul4(float4 a, float s) {
  a.x *= s; a.y *= s; a.z *= s; a.w *= s; return a;
}
// acc += dot(x[0:8], wf[0:8]); x is a 32B-aligned LDS row slice (broadcast reads)
__device__ __forceinline__ float acc8f(float acc, const float* x, const float* wf) {
  const float4* x4 = (const float4*)x;
  float4 a = x4[0], b = x4[1];
  acc = fmaf(a.x, wf[0], acc); acc = fmaf(a.y, wf[1], acc);
  acc = fmaf(a.z, wf[2], acc); acc = fmaf(a.w, wf[3], acc);
  acc = fmaf(b.x, wf[4], acc); acc = fmaf(b.y, wf[5], acc);
  acc = fmaf(b.z, wf[6], acc); acc = fmaf(b.w, wf[7], acc);
  return acc;
}
__device__ __forceinline__ void ld8(const float* p, float* f) {
  float4 a = *(const float4*)p, b = *(const float4*)(p + 4);
  f[0]=a.x; f[1]=a.y; f[2]=a.z; f[3]=a.w; f[4]=b.x; f[5]=b.y; f[6]=b.z; f[7]=b.w;
}

// ---------------- K1: long QKV projection (gather + pos add + 3 GEMV) ----------------
// long token: tok = l*512 + b ; l = t*16 + bh*4 + bw ; b = n*256 + ph*16 + pw
// out layout: qb/kb/vb[((b*8+hh)*64 + l)*16 + d]
__global__ __launch_bounds__(128) void k_proj_long(
    const float* __restrict__ q, const float* __restrict__ k,
    const float* __restrict__ v, const float* __restrict__ pq,
    const float* __restrict__ pk,
    const float* __restrict__ w_in, const float* __restrict__ b_in,
    float* __restrict__ qb, float* __restrict__ kb, float* __restrict__ vb) {
  __shared__ float xq[8][CC], xk[8][CC], xv[8][CC];
  const int tid = threadIdx.x;
  const int tok0 = blockIdx.x * 8;
  const int l = tok0 >> 9;
  const int t = l >> 4, bh = (l >> 2) & 3, bw = l & 3;
  const int b0 = tok0 & 511;                       // multiple of 8
  const int n = b0 >> 8, ph = (b0 >> 4) & 15, pw0 = b0 & 15;
  const int h = bh * 16 + ph, w0 = bw * 16 + pw0;
  const size_t base = (((size_t)(n * CC + tid) * 4 + t) << 12) + h * 64 + w0;
  {
    float a[8], p[8];
    ld8(q + base, a); ld8(pq + base, p);
#pragma unroll
    for (int tt = 0; tt < 8; ++tt) xq[tt][tid] = a[tt] + p[tt];
    ld8(k + base, a); ld8(pk + base, p);
#pragma unroll
    for (int tt = 0; tt < 8; ++tt) xk[tt][tid] = a[tt] + p[tt];
    ld8(v + base, a);
#pragma unroll
    for (int tt = 0; tt < 8; ++tt) xv[tt][tid] = a[tt];
  }
  __syncthreads();
  const int co = tid;
  float aq[8], ak[8], av[8];
  {
    float bq = b_in[co], bk = b_in[CC + co], bv = b_in[2 * CC + co];
#pragma unroll
    for (int tt = 0; tt < 8; ++tt) { aq[tt] = bq; ak[tt] = bk; av[tt] = bv; }
  }
  const float* wq = w_in + co * CC;
  const float* wk = w_in + (CC + co) * CC;
  const float* wv = w_in + (2 * CC + co) * CC;
  for (int c0 = 0; c0 < 16; ++c0) {
    float fq[8], fk[8], fv[8];
    ld8(wq + c0 * 8, fq); ld8(wk + c0 * 8, fk); ld8(wv + c0 * 8, fv);
#pragma unroll
    for (int tt = 0; tt < 8; ++tt) {
      aq[tt] = acc8f(aq[tt], &xq[tt][c0 * 8], fq);
      ak[tt] = acc8f(ak[tt], &xk[tt][c0 * 8], fk);
      av[tt] = acc8f(av[tt], &xv[tt][c0 * 8], fv);
    }
  }
  const int hh = co >> 4, d = co & 15;
#pragma unroll
  for (int tt = 0; tt < 8; ++tt) {
    int b = b0 + tt;
    size_t adr = ((size_t)(b * NHEADS + hh) * LLONG + l) * DHD + d;
    qb[adr] = aq[tt] * 0.25f;  // 1/sqrt(16)
    kb[adr] = ak[tt];
    vb[adr] = av[tt];
  }
}

// ---------------- K2: long attention (64 keys, exact softmax) ----------------
__global__ __launch_bounds__(64) void k_attn_long(
    const float* __restrict__ qb, const float* __restrict__ kb,
    const float* __restrict__ vb, float* __restrict__ ao) {
  __shared__ float ks[LLONG * DHD], vs[LLONG * DHD];
  const int tid = threadIdx.x;
  const int pair = blockIdx.x;  // b*8+hh
  const int b = pair >> 3, hh = pair & 7;
  const size_t base = (size_t)pair * (LLONG * DHD);
#pragma unroll
  for (int r = 0; r < 16; ++r) {
    int off = r * 64 + tid;
    ks[off] = kb[base + off];
    vs[off] = vb[base + off];
  }
  float4 q0, q1, q2, q3;
  {
    const float4* qp = (const float4*)(qb + base + tid * DHD);
    q0 = qp[0]; q1 = qp[1]; q2 = qp[2]; q3 = qp[3];
  }
  __syncthreads();
  const float4* k4 = (const float4*)ks;
  const float4* v4 = (const float4*)vs;
  float s[LLONG];
#pragma unroll
  for (int j = 0; j < LLONG; ++j) {
    float acc = dot4(q0, k4[j * 4 + 0], 0.f);
    acc = dot4(q1, k4[j * 4 + 1], acc);
    acc = dot4(q2, k4[j * 4 + 2], acc);
    s[j] = dot4(q3, k4[j * 4 + 3], acc);
  }
  float m = s[0];
#pragma unroll
  for (int j = 1; j < LLONG; ++j) m = fmaxf(m, s[j]);
  float sum = 0.f;
#pragma unroll
  for (int j = 0; j < LLONG; ++j) { s[j] = __expf(s[j] - m); sum += s[j]; }
  const float inv = 1.f / sum;
  float4 o0 = {0,0,0,0}, o1 = {0,0,0,0}, o2 = {0,0,0,0}, o3 = {0,0,0,0};
#pragma unroll
  for (int j = 0; j < LLONG; ++j) {
    float p = s[j];
    o0 = fma4(p, v4[j * 4 + 0], o0);
    o1 = fma4(p, v4[j * 4 + 1], o1);
    o2 = fma4(p, v4[j * 4 + 2], o2);
    o3 = fma4(p, v4[j * 4 + 3], o3);
  }
  // token-major store: tok = l*512+b, channel = hh*16+d
  size_t adr = ((size_t)tid * BLONG + b) * CC + hh * DHD;
  float4* aop = (float4*)(ao + adr);
  aop[0] = mul4(o0, inv); aop[1] = mul4(o1, inv);
  aop[2] = mul4(o2, inv); aop[3] = mul4(o3, inv);
}

// ---------------- K3: long out-proj + pos add + short QKV projection ----------------
// short: ls = t*256 + ph*16 + pw ; bs = n*16 + bh*4 + bw
__global__ __launch_bounds__(128) void k_mid(
    const float* __restrict__ ao, const float* __restrict__ pq,
    const float* __restrict__ w_out_l, const float* __restrict__ b_out_l,
    const float* __restrict__ w_in_s, const float* __restrict__ b_in_s,
    float* __restrict__ qb, float* __restrict__ kb, float* __restrict__ vb) {
  __shared__ float x[8][CC], yqk[8][CC], yv[8][CC];
  const int tid = threadIdx.x;
  const int tok0 = blockIdx.x * 8;
  const int l = tok0 >> 9;
  const int t = l >> 4, bh = (l >> 2) & 3, bw = l & 3;
  const int b0 = tok0 & 511;
  const int n = b0 >> 8, ph = (b0 >> 4) & 15, pw0 = b0 & 15;
  const int h = bh * 16 + ph, w0 = bw * 16 + pw0;
#pragma unroll
  for (int tt = 0; tt < 8; ++tt)
    x[tt][tid] = ao[(size_t)(tok0 + tt) * CC + tid];
  __syncthreads();
  {
    float acc[8];
    float bo = b_out_l[tid];
#pragma unroll
    for (int tt = 0; tt < 8; ++tt) acc[tt] = bo;
    const float* w = w_out_l + tid * CC;
    for (int c0 = 0; c0 < 16; ++c0) {
      float wf[8];
      ld8(w + c0 * 8, wf);
#pragma unroll
      for (int tt = 0; tt < 8; ++tt)
        acc[tt] = acc8f(acc[tt], &x[tt][c0 * 8], wf);
    }
    const size_t base = (((size_t)(n * CC + tid) * 4 + t) << 12) + h * 64 + w0;
    float p[8];
    ld8(pq + base, p);
#pragma unroll
    for (int tt = 0; tt < 8; ++tt) {
      yv[tt][tid] = acc[tt];
      yqk[tt][tid] = acc[tt] + p[tt];
    }
  }
  __syncthreads();
  const int co = tid;
  float aq[8], ak[8], av[8];
  {
    float bq = b_in_s[co], bk = b_in_s[CC + co], bv = b_in_s[2 * CC + co];
#pragma unroll
    for (int tt = 0; tt < 8; ++tt) { aq[tt] = bq; ak[tt] = bk; av[tt] = bv; }
  }
  const float* wq = w_in_s + co * CC;
  const float* wk = w_in_s + (CC + co) * CC;
  const float* wv = w_in_s + (2 * CC + co) * CC;
  for (int c0 = 0; c0 < 16; ++c0) {
    float fq[8], fk[8], fv[8];
    ld8(wq + c0 * 8, fq); ld8(wk + c0 * 8, fk); ld8(wv + c0 * 8, fv);
#pragma unroll
    for (int tt = 0; tt < 8; ++tt) {
      aq[tt] = acc8f(aq[tt], &yqk[tt][c0 * 8], fq);
      ak[tt] = acc8f(ak[tt], &yqk[tt][c0 * 8], fk);
      av[tt] = acc8f(av[tt], &yv[tt][c0 * 8], fv);
    }
  }
  const int hh = co >> 4, d = co & 15;
#pragma unroll
  for (int tt = 0; tt < 8; ++tt) {
    int b = b0 + tt;
    int php = (b >> 4) & 15, pwp = b & 15;
    int ls = (t * 16 + php) * 16 + pwp;
    int bs = (b >> 8) * 16 + bh * 4 + bw;
    size_t adr = ((size_t)(bs * NHEADS + hh) * LSHORT + ls) * DHD + d;
    qb[adr] = aq[tt] * 0.25f;
    kb[adr] = ak[tt];
    vb[adr] = av[tt];
  }
}

// ---------------- K4: short attention (1024 keys, online softmax) ----------------
__global__ __launch_bounds__(256) void k_attn_short(
    const float* __restrict__ qb, const float* __restrict__ kb,
    const float* __restrict__ vb, float* __restrict__ ao) {
  __shared__ float ks[128 * DHD], vs[128 * DHD];
  const int tid = threadIdx.x;
  const int pair = blockIdx.x >> 2;  // bs*8+hh
  const int qt = blockIdx.x & 3;
  const int bs = pair >> 3, hh = pair & 7;
  const size_t base = (size_t)pair * (LSHORT * DHD);
  const int qi = qt * 256 + tid;
  float4 q0, q1, q2, q3;
  {
    const float4* qp = (const float4*)(qb + base + (size_t)qi * DHD);
    q0 = qp[0]; q1 = qp[1]; q2 = qp[2]; q3 = qp[3];
  }
  float m = -3.0e38f, lsum = 0.f;
  float4 o0 = {0,0,0,0}, o1 = {0,0,0,0}, o2 = {0,0,0,0}, o3 = {0,0,0,0};
  const float4* k4 = (const float4*)ks;
  const float4* v4 = (const float4*)vs;
  for (int kt = 0; kt < 8; ++kt) {
    __syncthreads();
#pragma unroll
    for (int r = 0; r < 8; ++r) {
      int off = r * 256 + tid;
      ks[off] = kb[base + kt * 2048 + off];
      vs[off] = vb[base + kt * 2048 + off];
    }
    __syncthreads();
    for (int j0 = 0; j0 < 128; j0 += 16) {
      float s[16];
#pragma unroll
      for (int j = 0; j < 16; ++j) {
        int row = (j0 + j) * 4;
        float acc = dot4(q0, k4[row], 0.f);
        acc = dot4(q1, k4[row + 1], acc);
        acc = dot4(q2, k4[row + 2], acc);
        s[j] = dot4(q3, k4[row + 3], acc);
      }
      float cm = s[0];
#pragma unroll
      for (int j = 1; j < 16; ++j) cm = fmaxf(cm, s[j]);
      float mnew = fmaxf(m, cm);
      float scale = __expf(m - mnew);
      lsum *= scale;
      o0 = mul4(o0, scale); o1 = mul4(o1, scale);
      o2 = mul4(o2, scale); o3 = mul4(o3, scale);
#pragma unroll
      for (int j = 0; j < 16; ++j) {
        float p = __expf(s[j] - mnew);
        lsum += p;
        int row = (j0 + j) * 4;
        o0 = fma4(p, v4[row], o0);
        o1 = fma4(p, v4[row + 1], o1);
        o2 = fma4(p, v4[row + 2], o2);
        o3 = fma4(p, v4[row + 3], o3);
      }
      m = mnew;
    }
  }
  const float inv = 1.f / lsum;
  size_t adr = ((size_t)qi * BSHORT + bs) * CC + hh * DHD;
  float4* aop = (float4*)(ao + adr);
  aop[0] = mul4(o0, inv); aop[1] = mul4(o1, inv);
  aop[2] = mul4(o2, inv); aop[3] = mul4(o3, inv);
}

// ---------------- K5: short out-proj + scatter to (N,C,T,H,W) fp32 ----------------
__global__ __launch_bounds__(128) void k_out_short(
    const float* __restrict__ ao, const float* __restrict__ w_out,
    const float* __restrict__ b_out, float* __restrict__ out) {
  __shared__ float x[64][CC];
  const int tid = threadIdx.x;
  const int bid = blockIdx.x;  // (n,t,h)
  const int n = bid >> 8;
  const int t = (bid >> 6) & 3;
  const int h = bid & 63;
  const int bh = h >> 4, ph = h & 15;
  for (int w = 0; w < 64; ++w) {
    int pw = w & 15, bw = w >> 4;
    int ls = (t * 16 + ph) * 16 + pw;
    int bs = n * 16 + bh * 4 + bw;
    x[w][tid] = ao[(size_t)(ls * BSHORT + bs) * CC + tid];
  }
  __syncthreads();
  const int co = tid;
  const float bo = b_out[co];
  const float* wr = w_out + co * CC;
  const size_t obase0 = (((size_t)(n * CC + co) * 4 + t) << 12) + h * 64;
  for (int wc = 0; wc < 4; ++wc) {
    float acc[16];
#pragma unroll
    for (int j = 0; j < 16; ++j) acc[j] = bo;
    for (int c0 = 0; c0 < 16; ++c0) {
      float wf[8];
      ld8(wr + c0 * 8, wf);
#pragma unroll
      for (int j = 0; j < 16; ++j)
        acc[j] = acc8f(acc[j], &x[wc * 16 + j][c0 * 8], wf);
    }
#pragma unroll
    for (int j4 = 0; j4 < 4; ++j4) {
      float4 f;
      f.x = acc[j4 * 4 + 0]; f.y = acc[j4 * 4 + 1];
      f.z = acc[j4 * 4 + 2]; f.w = acc[j4 * 4 + 3];
      *(float4*)(out + obase0 + wc * 16 + j4 * 4) = f;
    }
  }
}

extern "C" void kernel_launch(void* const* d_in, const int* in_sizes, int n_in,
                              void* d_out, int out_size, void* d_ws, size_t ws_size,
                              hipStream_t stream) {
  (void)in_sizes; (void)n_in; (void)out_size; (void)ws_size;
  const float* q   = (const float*)d_in[0];
  const float* k   = (const float*)d_in[1];
  const float* v   = (const float*)d_in[2];
  const float* pq  = (const float*)d_in[3];
  const float* pk  = (const float*)d_in[4];
  const float* wil = (const float*)d_in[5];
  const float* bil = (const float*)d_in[6];
  const float* wol = (const float*)d_in[7];
  const float* bol = (const float*)d_in[8];
  const float* wis = (const float*)d_in[9];
  const float* bis = (const float*)d_in[10];
  const float* wos = (const float*)d_in[11];
  const float* bos = (const float*)d_in[12];

  float* qbuf  = (float*)d_ws;            // 4M floats each
  float* kbuf  = qbuf + 4194304;
  float* vbuf  = kbuf + 4194304;
  float* aobuf = vbuf + 4194304;

  k_proj_long<<<dim3(4096), dim3(128), 0, stream>>>(q, k, v, pq, pk, wil, bil,
                                                    qbuf, kbuf, vbuf);
  k_attn_long<<<dim3(4096), dim3(64), 0, stream>>>(qbuf, kbuf, vbuf, aobuf);
  k_mid<<<dim3(4096), dim3(128), 0, stream>>>(aobuf, pq, wol, bol, wis, bis,
                                              qbuf, kbuf, vbuf);
  k_attn_short<<<dim3(1024), dim3(256), 0, stream>>>(qbuf, kbuf, vbuf, aobuf);
  k_out_short<<<dim3(512), dim3(128), 0, stream>>>(aobuf, wos, bos,
                                                   (float*)d_out);
}

// Round 4
// 429.524 us; speedup vs baseline: 1.4497x; 1.4497x over previous
//
#include <hip/hip_runtime.h>

#define CC 128
#define NHEADS 8
#define DHD 16
#define LLONG 64
#define BLONG 512
#define LSHORT 1024
#define BSHORT 32

typedef __attribute__((ext_vector_type(8))) short short8;
typedef __attribute__((ext_vector_type(16))) float f32x16;

__device__ __forceinline__ float dot4(float4 a, float4 b, float acc) {
  acc = fmaf(a.x, b.x, acc); acc = fmaf(a.y, b.y, acc);
  acc = fmaf(a.z, b.z, acc); acc = fmaf(a.w, b.w, acc);
  return acc;
}
__device__ __forceinline__ float4 fma4(float p, float4 v, float4 o) {
  o.x = fmaf(p, v.x, o.x); o.y = fmaf(p, v.y, o.y);
  o.z = fmaf(p, v.z, o.z); o.w = fmaf(p, v.w, o.w);
  return o;
}
__device__ __forceinline__ float4 mul4(float4 a, float s) {
  a.x *= s; a.y *= s; a.z *= s; a.w *= s; return a;
}
__device__ __forceinline__ float acc8f(float acc, const float* x, const float* wf) {
  const float4* x4 = (const float4*)x;
  float4 a = x4[0], b = x4[1];
  acc = fmaf(a.x, wf[0], acc); acc = fmaf(a.y, wf[1], acc);
  acc = fmaf(a.z, wf[2], acc); acc = fmaf(a.w, wf[3], acc);
  acc = fmaf(b.x, wf[4], acc); acc = fmaf(b.y, wf[5], acc);
  acc = fmaf(b.z, wf[6], acc); acc = fmaf(b.w, wf[7], acc);
  return acc;
}
__device__ __forceinline__ void ld8(const float* p, float* f) {
  float4 a = *(const float4*)p, b = *(const float4*)(p + 4);
  f[0]=a.x; f[1]=a.y; f[2]=a.z; f[3]=a.w; f[4]=b.x; f[5]=b.y; f[6]=b.z; f[7]=b.w;
}
__device__ __forceinline__ short f2bfs(float f) {
  union { float f; unsigned int i; } x; x.f = f;
  unsigned int r = x.i + 0x7fffu + ((x.i >> 16) & 1u);
  return (short)(r >> 16);
}
__device__ __forceinline__ f32x16 fzero16() {
  f32x16 z;
#pragma unroll
  for (int i = 0; i < 16; ++i) z[i] = 0.f;
  return z;
}

// ---------------- K1: long QKV projection (gather + pos add + 3 GEMV) ----------------
__global__ __launch_bounds__(128) void k_proj_long(
    const float* __restrict__ q, const float* __restrict__ k,
    const float* __restrict__ v, const float* __restrict__ pq,
    const float* __restrict__ pk,
    const float* __restrict__ w_in, const float* __restrict__ b_in,
    float* __restrict__ qb, float* __restrict__ kb, float* __restrict__ vb) {
  __shared__ float xq[8][CC], xk[8][CC], xv[8][CC];
  const int tid = threadIdx.x;
  const int tok0 = blockIdx.x * 8;
  const int l = tok0 >> 9;
  const int t = l >> 4, bh = (l >> 2) & 3, bw = l & 3;
  const int b0 = tok0 & 511;
  const int n = b0 >> 8, ph = (b0 >> 4) & 15, pw0 = b0 & 15;
  const int h = bh * 16 + ph, w0 = bw * 16 + pw0;
  const size_t base = (((size_t)(n * CC + tid) * 4 + t) << 12) + h * 64 + w0;
  {
    float a[8], p[8];
    ld8(q + base, a); ld8(pq + base, p);
#pragma unroll
    for (int tt = 0; tt < 8; ++tt) xq[tt][tid] = a[tt] + p[tt];
    ld8(k + base, a); ld8(pk + base, p);
#pragma unroll
    for (int tt = 0; tt < 8; ++tt) xk[tt][tid] = a[tt] + p[tt];
    ld8(v + base, a);
#pragma unroll
    for (int tt = 0; tt < 8; ++tt) xv[tt][tid] = a[tt];
  }
  __syncthreads();
  const int co = tid;
  float aq[8], ak[8], av[8];
  {
    float bq = b_in[co], bk = b_in[CC + co], bv = b_in[2 * CC + co];
#pragma unroll
    for (int tt = 0; tt < 8; ++tt) { aq[tt] = bq; ak[tt] = bk; av[tt] = bv; }
  }
  const float* wq = w_in + co * CC;
  const float* wk = w_in + (CC + co) * CC;
  const float* wv = w_in + (2 * CC + co) * CC;
  for (int c0 = 0; c0 < 16; ++c0) {
    float fq[8], fk[8], fv[8];
    ld8(wq + c0 * 8, fq); ld8(wk + c0 * 8, fk); ld8(wv + c0 * 8, fv);
#pragma unroll
    for (int tt = 0; tt < 8; ++tt) {
      aq[tt] = acc8f(aq[tt], &xq[tt][c0 * 8], fq);
      ak[tt] = acc8f(ak[tt], &xk[tt][c0 * 8], fk);
      av[tt] = acc8f(av[tt], &xv[tt][c0 * 8], fv);
    }
  }
  const int hh = co >> 4, d = co & 15;
#pragma unroll
  for (int tt = 0; tt < 8; ++tt) {
    int b = b0 + tt;
    size_t adr = ((size_t)(b * NHEADS + hh) * LLONG + l) * DHD + d;
    qb[adr] = aq[tt] * 0.25f;
    kb[adr] = ak[tt];
    vb[adr] = av[tt];
  }
}

// ---------------- K2: long attention (64 keys, exact softmax, fp32) ----------------
__global__ __launch_bounds__(64) void k_attn_long(
    const float* __restrict__ qb, const float* __restrict__ kb,
    const float* __restrict__ vb, float* __restrict__ ao) {
  __shared__ float ks[LLONG * DHD], vs[LLONG * DHD];
  const int tid = threadIdx.x;
  const int pair = blockIdx.x;
  const int b = pair >> 3, hh = pair & 7;
  const size_t base = (size_t)pair * (LLONG * DHD);
#pragma unroll
  for (int r = 0; r < 16; ++r) {
    int off = r * 64 + tid;
    ks[off] = kb[base + off];
    vs[off] = vb[base + off];
  }
  float4 q0, q1, q2, q3;
  {
    const float4* qp = (const float4*)(qb + base + tid * DHD);
    q0 = qp[0]; q1 = qp[1]; q2 = qp[2]; q3 = qp[3];
  }
  __syncthreads();
  const float4* k4 = (const float4*)ks;
  const float4* v4 = (const float4*)vs;
  float s[LLONG];
#pragma unroll
  for (int j = 0; j < LLONG; ++j) {
    float acc = dot4(q0, k4[j * 4 + 0], 0.f);
    acc = dot4(q1, k4[j * 4 + 1], acc);
    acc = dot4(q2, k4[j * 4 + 2], acc);
    s[j] = dot4(q3, k4[j * 4 + 3], acc);
  }
  float m = s[0];
#pragma unroll
  for (int j = 1; j < LLONG; ++j) m = fmaxf(m, s[j]);
  float sum = 0.f;
#pragma unroll
  for (int j = 0; j < LLONG; ++j) { s[j] = __expf(s[j] - m); sum += s[j]; }
  const float inv = 1.f / sum;
  float4 o0 = {0,0,0,0}, o1 = {0,0,0,0}, o2 = {0,0,0,0}, o3 = {0,0,0,0};
#pragma unroll
  for (int j = 0; j < LLONG; ++j) {
    float p = s[j];
    o0 = fma4(p, v4[j * 4 + 0], o0);
    o1 = fma4(p, v4[j * 4 + 1], o1);
    o2 = fma4(p, v4[j * 4 + 2], o2);
    o3 = fma4(p, v4[j * 4 + 3], o3);
  }
  size_t adr = ((size_t)tid * BLONG + b) * CC + hh * DHD;
  float4* aop = (float4*)(ao + adr);
  aop[0] = mul4(o0, inv); aop[1] = mul4(o1, inv);
  aop[2] = mul4(o2, inv); aop[3] = mul4(o3, inv);
}

// ---------------- K3: long out-proj + pos add + short QKV proj -> bf16 ----------------
__global__ __launch_bounds__(128) void k_mid(
    const float* __restrict__ ao, const float* __restrict__ pq,
    const float* __restrict__ w_out_l, const float* __restrict__ b_out_l,
    const float* __restrict__ w_in_s, const float* __restrict__ b_in_s,
    short* __restrict__ qb, short* __restrict__ kb, short* __restrict__ vb) {
  __shared__ float x[8][CC], yqk[8][CC], yv[8][CC];
  const int tid = threadIdx.x;
  const int tok0 = blockIdx.x * 8;
  const int l = tok0 >> 9;
  const int t = l >> 4, bh = (l >> 2) & 3, bw = l & 3;
  const int b0 = tok0 & 511;
  const int n = b0 >> 8, ph = (b0 >> 4) & 15, pw0 = b0 & 15;
  const int h = bh * 16 + ph, w0 = bw * 16 + pw0;
#pragma unroll
  for (int tt = 0; tt < 8; ++tt)
    x[tt][tid] = ao[(size_t)(tok0 + tt) * CC + tid];
  __syncthreads();
  {
    float acc[8];
    float bo = b_out_l[tid];
#pragma unroll
    for (int tt = 0; tt < 8; ++tt) acc[tt] = bo;
    const float* w = w_out_l + tid * CC;
    for (int c0 = 0; c0 < 16; ++c0) {
      float wf[8];
      ld8(w + c0 * 8, wf);
#pragma unroll
      for (int tt = 0; tt < 8; ++tt)
        acc[tt] = acc8f(acc[tt], &x[tt][c0 * 8], wf);
    }
    const size_t base = (((size_t)(n * CC + tid) * 4 + t) << 12) + h * 64 + w0;
    float p[8];
    ld8(pq + base, p);
#pragma unroll
    for (int tt = 0; tt < 8; ++tt) {
      yv[tt][tid] = acc[tt];
      yqk[tt][tid] = acc[tt] + p[tt];
    }
  }
  __syncthreads();
  const int co = tid;
  float aq[8], ak[8], av[8];
  {
    float bq = b_in_s[co], bk = b_in_s[CC + co], bv = b_in_s[2 * CC + co];
#pragma unroll
    for (int tt = 0; tt < 8; ++tt) { aq[tt] = bq; ak[tt] = bk; av[tt] = bv; }
  }
  const float* wq = w_in_s + co * CC;
  const float* wk = w_in_s + (CC + co) * CC;
  const float* wv = w_in_s + (2 * CC + co) * CC;
  for (int c0 = 0; c0 < 16; ++c0) {
    float fq[8], fk[8], fv[8];
    ld8(wq + c0 * 8, fq); ld8(wk + c0 * 8, fk); ld8(wv + c0 * 8, fv);
#pragma unroll
    for (int tt = 0; tt < 8; ++tt) {
      aq[tt] = acc8f(aq[tt], &yqk[tt][c0 * 8], fq);
      ak[tt] = acc8f(ak[tt], &yqk[tt][c0 * 8], fk);
      av[tt] = acc8f(av[tt], &yv[tt][c0 * 8], fv);
    }
  }
  const int hh = co >> 4, d = co & 15;
#pragma unroll
  for (int tt = 0; tt < 8; ++tt) {
    int b = b0 + tt;
    int php = (b >> 4) & 15, pwp = b & 15;
    int ls = (t * 16 + php) * 16 + pwp;
    int bs = (b >> 8) * 16 + bh * 4 + bw;
    size_t adr = ((size_t)(bs * NHEADS + hh) * LSHORT + ls) * DHD + d;
    qb[adr] = f2bfs(aq[tt] * 0.25f);
    kb[adr] = f2bfs(ak[tt]);
    vb[adr] = f2bfs(av[tt]);
  }
}

// ---------------- K4: short attention, MFMA bf16 flash ----------------
// Per wave: 32 queries. S^T = mfma_32x32x16(K_tile, Q): C col = query(lane&31),
// C row r -> key (r&3)+8*(r>>2)+4*(lane>>5). S-regs 0-7 / 8-15 are exactly the
// two PV B-fragments (slot (g,j) -> key {4g+j, 8+4g+j} / +16). A = V^T from
// per-wave LDS scratch ([16][36] bf16, conflict-free). O^T C: regs 0-7 give
// d = {4g..4g+3, 8+4g..11+4g} for this lane's query. lane<->lane^32 share a
// query's softmax state (shfl_xor 32).
__global__ __launch_bounds__(256) void k_attn_short_mfma(
    const short* __restrict__ qs, const short* __restrict__ ks,
    const short* __restrict__ vs, float* __restrict__ ao) {
  __shared__ short vt[4][16 * 36];
  const int tid = threadIdx.x;
  const int wid = tid >> 6, lane = tid & 63;
  const int l31 = lane & 31, g = lane >> 5;
  const int pair = blockIdx.x >> 3;      // bs*8+hh
  const int qc = blockIdx.x & 7;
  const int bs = pair >> 3, hh = pair & 7;
  const size_t pbase = (size_t)pair * (LSHORT * DHD);
  const int q0 = qc * 128 + wid * 32;
  short* vtw = &vt[wid][0];

  const short8 qf = *(const short8*)(qs + pbase + (size_t)(q0 + l31) * DHD + 8 * g);

  f32x16 acc = fzero16();
  float m = -3.0e38f, lsum = 0.f;

  for (int k0 = 0; k0 < LSHORT; k0 += 32) {
    const short8 kf = *(const short8*)(ks + pbase + (size_t)(k0 + l31) * DHD + 8 * g);
    const short8 vf = *(const short8*)(vs + pbase + (size_t)(k0 + l31) * DHD + 8 * g);
#pragma unroll
    for (int j = 0; j < 8; ++j)
      vtw[(8 * g + j) * 36 + l31] = vf[j];

    f32x16 s = __builtin_amdgcn_mfma_f32_32x32x16_bf16(kf, qf, fzero16(), 0, 0, 0);

    // joint (lane, lane^32) tile max
    float t8[8];
#pragma unroll
    for (int r = 0; r < 8; ++r) t8[r] = fmaxf(s[r], s[r + 8]);
#pragma unroll
    for (int r = 0; r < 4; ++r) t8[r] = fmaxf(t8[r], t8[r + 4]);
    float tmax = fmaxf(fmaxf(t8[0], t8[1]), fmaxf(t8[2], t8[3]));
    tmax = fmaxf(tmax, __shfl_xor(tmax, 32, 64));
    const float mnew = fmaxf(m, tmax);
    const float scale = __expf(m - mnew);
    m = mnew;
    lsum *= scale;
#pragma unroll
    for (int r = 0; r < 8; ++r) acc[r] *= scale;

    float p[16];
    float psum = 0.f;
#pragma unroll
    for (int r = 0; r < 16; ++r) { p[r] = __expf(s[r] - mnew); psum += p[r]; }
    lsum += psum;

    short8 pa, pb;
#pragma unroll
    for (int j = 0; j < 8; ++j) { pa[j] = f2bfs(p[j]); pb[j] = f2bfs(p[8 + j]); }

    const short* vtr = vtw + (l31 & 15) * 36;
    union { int4 i; short8 s8; } a1, a2;
    {
      int2 lo = *(const int2*)(vtr + 4 * g);
      int2 hi = *(const int2*)(vtr + 8 + 4 * g);
      a1.i.x = lo.x; a1.i.y = lo.y; a1.i.z = hi.x; a1.i.w = hi.y;
      int2 lo2 = *(const int2*)(vtr + 16 + 4 * g);
      int2 hi2 = *(const int2*)(vtr + 24 + 4 * g);
      a2.i.x = lo2.x; a2.i.y = lo2.y; a2.i.z = hi2.x; a2.i.w = hi2.y;
    }
    acc = __builtin_amdgcn_mfma_f32_32x32x16_bf16(a1.s8, pa, acc, 0, 0, 0);
    acc = __builtin_amdgcn_mfma_f32_32x32x16_bf16(a2.s8, pb, acc, 0, 0, 0);
  }

  const float total = lsum + __shfl_xor(lsum, 32, 64);
  const float inv = 1.f / total;
  float4 o1, o2;
  o1.x = acc[0] * inv; o1.y = acc[1] * inv; o1.z = acc[2] * inv; o1.w = acc[3] * inv;
  o2.x = acc[4] * inv; o2.y = acc[5] * inv; o2.z = acc[6] * inv; o2.w = acc[7] * inv;
  const int qi = q0 + l31;
  float* dst = ao + ((size_t)qi * BSHORT + bs) * CC + hh * DHD;
  *(float4*)(dst + 4 * g) = o1;
  *(float4*)(dst + 8 + 4 * g) = o2;
}

// ---------------- K5: short out-proj + scatter to (N,C,T,H,W) fp32 ----------------
__global__ __launch_bounds__(128) void k_out_short(
    const float* __restrict__ ao, const float* __restrict__ w_out,
    const float* __restrict__ b_out, float* __restrict__ out) {
  __shared__ float x[64][CC];
  const int tid = threadIdx.x;
  const int bid = blockIdx.x;
  const int n = bid >> 8;
  const int t = (bid >> 6) & 3;
  const int h = bid & 63;
  const int bh = h >> 4, ph = h & 15;
  for (int w = 0; w < 64; ++w) {
    int pw = w & 15, bw = w >> 4;
    int ls = (t * 16 + ph) * 16 + pw;
    int bs = n * 16 + bh * 4 + bw;
    x[w][tid] = ao[(size_t)(ls * BSHORT + bs) * CC + tid];
  }
  __syncthreads();
  const int co = tid;
  const float bo = b_out[co];
  const float* wr = w_out + co * CC;
  const size_t obase0 = (((size_t)(n * CC + co) * 4 + t) << 12) + h * 64;
  for (int wc = 0; wc < 4; ++wc) {
    float acc[16];
#pragma unroll
    for (int j = 0; j < 16; ++j) acc[j] = bo;
    for (int c0 = 0; c0 < 16; ++c0) {
      float wf[8];
      ld8(wr + c0 * 8, wf);
#pragma unroll
      for (int j = 0; j < 16; ++j)
        acc[j] = acc8f(acc[j], &x[wc * 16 + j][c0 * 8], wf);
    }
#pragma unroll
    for (int j4 = 0; j4 < 4; ++j4) {
      float4 f;
      f.x = acc[j4 * 4 + 0]; f.y = acc[j4 * 4 + 1];
      f.z = acc[j4 * 4 + 2]; f.w = acc[j4 * 4 + 3];
      *(float4*)(out + obase0 + wc * 16 + j4 * 4) = f;
    }
  }
}

extern "C" void kernel_launch(void* const* d_in, const int* in_sizes, int n_in,
                              void* d_out, int out_size, void* d_ws, size_t ws_size,
                              hipStream_t stream) {
  (void)in_sizes; (void)n_in; (void)out_size; (void)ws_size;
  const float* q   = (const float*)d_in[0];
  const float* k   = (const float*)d_in[1];
  const float* v   = (const float*)d_in[2];
  const float* pq  = (const float*)d_in[3];
  const float* pk  = (const float*)d_in[4];
  const float* wil = (const float*)d_in[5];
  const float* bil = (const float*)d_in[6];
  const float* wol = (const float*)d_in[7];
  const float* bol = (const float*)d_in[8];
  const float* wis = (const float*)d_in[9];
  const float* bis = (const float*)d_in[10];
  const float* wos = (const float*)d_in[11];
  const float* bos = (const float*)d_in[12];

  float* qbuf  = (float*)d_ws;            // 4M floats each
  float* kbuf  = qbuf + 4194304;
  float* vbuf  = kbuf + 4194304;
  float* aobuf = vbuf + 4194304;
  // bf16 short-stage QKV reuse the (dead after k_attn_long) fp32 regions
  short* qs16 = (short*)qbuf;
  short* ks16 = (short*)kbuf;
  short* vs16 = (short*)vbuf;

  k_proj_long<<<dim3(4096), dim3(128), 0, stream>>>(q, k, v, pq, pk, wil, bil,
                                                    qbuf, kbuf, vbuf);
  k_attn_long<<<dim3(4096), dim3(64), 0, stream>>>(qbuf, kbuf, vbuf, aobuf);
  k_mid<<<dim3(4096), dim3(128), 0, stream>>>(aobuf, pq, wol, bol, wis, bis,
                                              qs16, ks16, vs16);
  k_attn_short_mfma<<<dim3(2048), dim3(256), 0, stream>>>(qs16, ks16, vs16, aobuf);
  k_out_short<<<dim3(512), dim3(128), 0, stream>>>(aobuf, wos, bos,
                                                   (float*)d_out);
}

// Round 5
// 177.794 us; speedup vs baseline: 3.5024x; 2.4158x over previous
//
#include <hip/hip_runtime.h>

#define CC 128

typedef __attribute__((ext_vector_type(8))) short short8;
typedef __attribute__((ext_vector_type(16))) float f32x16;

union I4S8 { int4 i; short8 s; int2 h[2]; };

__device__ __forceinline__ unsigned short f2bfu(float f) {
  union { float f; unsigned int i; } x; x.f = f;
  unsigned int r = x.i + 0x7fffu + ((x.i >> 16) & 1u);
  return (unsigned short)(r >> 16);
}
__device__ __forceinline__ short f2bfs(float f) { return (short)f2bfu(f); }
__device__ __forceinline__ unsigned int pack2(float a, float b) {
  return (unsigned int)f2bfu(a) | ((unsigned int)f2bfu(b) << 16);
}
__device__ __forceinline__ float bflo(unsigned int u) {
  union { unsigned int i; float f; } x; x.i = u << 16; return x.f;
}
__device__ __forceinline__ float bfhi(unsigned int u) {
  union { unsigned int i; float f; } x; x.i = u & 0xffff0000u; return x.f;
}
__device__ __forceinline__ f32x16 fzero16() {
  f32x16 z;
#pragma unroll
  for (int i = 0; i < 16; ++i) z[i] = 0.f;
  return z;
}
__device__ __forceinline__ void ld16(const float* p, float* f) {
#pragma unroll
  for (int i = 0; i < 4; ++i) {
    float4 a = *(const float4*)(p + 4 * i);
    f[4*i] = a.x; f[4*i+1] = a.y; f[4*i+2] = a.z; f[4*i+3] = a.w;
  }
}

// ---------------- W: fp32 -> bf16 weight conversion (once per launch) ----------------
// wbf layout: w_in_long @0 (49152), w_out_long @49152 (16384),
//             w_in_short @65536 (49152), w_out_short @114688 (16384)
__global__ __launch_bounds__(256) void k_cvtw(
    const float* __restrict__ wil, const float* __restrict__ wol,
    const float* __restrict__ wis, const float* __restrict__ wos,
    short* __restrict__ o) {
  const int idx = (blockIdx.x * 256 + threadIdx.x) * 8;
  const float* src; int off;
  if (idx < 49152)       { src = wil; off = idx; }
  else if (idx < 65536)  { src = wol; off = idx - 49152; }
  else if (idx < 114688) { src = wis; off = idx - 65536; }
  else                   { src = wos; off = idx - 114688; }
  float f[8];
  float4 a = *(const float4*)(src + off), b = *(const float4*)(src + off + 4);
  f[0]=a.x; f[1]=a.y; f[2]=a.z; f[3]=a.w; f[4]=b.x; f[5]=b.y; f[6]=b.z; f[7]=b.w;
  short8 r;
#pragma unroll
  for (int j = 0; j < 8; ++j) r[j] = f2bfs(f[j]);
  *(short8*)(o + idx) = r;
}

// ---------------- K1: long QKV projection, MFMA ----------------
// tile = 32 long-tokens (fixed l, b0..b0+31). Emits bf16 long QKV
// [pair=b*8+hh][l][d] and pos_ct[c][tok] bf16.
__global__ __launch_bounds__(256) void k_proj_long(
    const float* __restrict__ q, const float* __restrict__ k,
    const float* __restrict__ v, const float* __restrict__ pq,
    const float* __restrict__ pk,
    const short* __restrict__ wbf, const float* __restrict__ b_in,
    short* __restrict__ qb, short* __restrict__ kb, short* __restrict__ vb,
    short* __restrict__ pos_ct) {
  __shared__ short XQ[32][132], XK[32][132], XV[32][132];
  const int tid = threadIdx.x;
  const int wid = tid >> 6, lane = tid & 63;
  const int l31 = lane & 31, g = lane >> 5;
  const int tok0 = blockIdx.x * 32;
  const int l = tok0 >> 9, b0 = tok0 & 511;
  const int t = l >> 4, bh = (l >> 2) & 3, bw = l & 3;
  const int nb = b0 >> 8, ph0 = (b0 >> 4) & 15;
  // ---- stage: thread (c, half) loads 16 consecutive w pixels of channel c
  {
    const int c = tid >> 1, half = tid & 1;
    const int h = bh * 16 + ph0 + half, w0 = bw * 16;
    const size_t gb = (((size_t)(nb * CC + c) * 4 + t) << 12) + h * 64 + w0;
    float a[16], p[16];
    ld16(q + gb, a); ld16(pq + gb, p);
    {
      short8 s0, s1;
#pragma unroll
      for (int j = 0; j < 8; ++j) { s0[j] = f2bfs(p[j]); s1[j] = f2bfs(p[8 + j]); }
      short* pd = pos_ct + (size_t)c * 32768 + tok0 + half * 16;
      *(short8*)pd = s0;
      *(short8*)(pd + 8) = s1;
    }
#pragma unroll
    for (int j = 0; j < 16; ++j) XQ[half * 16 + j][c] = f2bfs(a[j] + p[j]);
    ld16(k + gb, a); ld16(pk + gb, p);
#pragma unroll
    for (int j = 0; j < 16; ++j) XK[half * 16 + j][c] = f2bfs(a[j] + p[j]);
    ld16(v + gb, a);
#pragma unroll
    for (int j = 0; j < 16; ++j) XV[half * 16 + j][c] = f2bfs(a[j]);
  }
  __syncthreads();
  // ---- GEMM: wave does 3 n-tiles (one per projection)
  for (int i = 0; i < 3; ++i) {
    const int nt = wid + 4 * i;
    const int nch = nt * 32 + l31;          // 0..383 row of w_in_long
    const int which = nt >> 2;              // 0=q 1=k 2=v
    const short (*X)[132] = (which == 0) ? XQ : (which == 1) ? XK : XV;
    f32x16 acc = fzero16();
#pragma unroll
    for (int k0 = 0; k0 < 128; k0 += 16) {
      I4S8 af;
      af.h[0] = *(const int2*)&X[l31][k0 + 8 * g];
      af.h[1] = *(const int2*)&X[l31][k0 + 8 * g + 4];
      short8 bf = *(const short8*)(wbf + nch * CC + k0 + 8 * g);
      acc = __builtin_amdgcn_mfma_f32_32x32x16_bf16(af.s, bf, acc, 0, 0, 0);
    }
    const float bias = b_in[nch];
    const float qsc = (which == 0) ? 0.25f : 1.0f;
    const int hh = (nch >> 4) & 7, d = nch & 15;
    short* dst = (which == 0) ? qb : (which == 1) ? kb : vb;
#pragma unroll
    for (int r = 0; r < 16; ++r) {
      const int tt = (r & 3) + 8 * (r >> 2) + 4 * g;
      const int b = b0 + tt;
      dst[((size_t)(b * 8 + hh) * 64 + l) * 16 + d] = f2bfs((acc[r] + bias) * qsc);
    }
  }
}

// ---------------- K2: unified MFMA flash attention ----------------
// bf16 in/out. Per wave 32 queries; S^T = mfma(K,Q); online softmax with
// lane<->lane^32 pairing; PV via per-wave V^T LDS scratch.
// out: ao[(qi*BATCH + batch)*128 + hh*16 + d] bf16.
template<int SEQ, int BATCH>
__global__ __launch_bounds__(256) void k_attn(
    const short* __restrict__ qsp, const short* __restrict__ ksp,
    const short* __restrict__ vsp, short* __restrict__ ao) {
  __shared__ short vt[4][16 * 36];
  const int tid = threadIdx.x;
  const int wid = tid >> 6, lane = tid & 63;
  const int l31 = lane & 31, g = lane >> 5;
  const int WPP = SEQ / 32;
  const int gw = blockIdx.x * 4 + wid;
  const int pair = gw / WPP;
  const int q0 = (gw % WPP) * 32;
  const int batch = pair >> 3, hh = pair & 7;
  const size_t pbase = (size_t)pair * (SEQ * 16);
  short* vtw = &vt[wid][0];

  const short8 qf = *(const short8*)(qsp + pbase + (size_t)(q0 + l31) * 16 + 8 * g);

  f32x16 acc = fzero16();
  float m = -3.0e38f, lsum = 0.f;

  for (int k0 = 0; k0 < SEQ; k0 += 32) {
    const short8 kf = *(const short8*)(ksp + pbase + (size_t)(k0 + l31) * 16 + 8 * g);
    const short8 vf = *(const short8*)(vsp + pbase + (size_t)(k0 + l31) * 16 + 8 * g);
#pragma unroll
    for (int j = 0; j < 8; ++j)
      vtw[(8 * g + j) * 36 + l31] = vf[j];

    f32x16 s = __builtin_amdgcn_mfma_f32_32x32x16_bf16(kf, qf, fzero16(), 0, 0, 0);

    float t8[8];
#pragma unroll
    for (int r = 0; r < 8; ++r) t8[r] = fmaxf(s[r], s[r + 8]);
#pragma unroll
    for (int r = 0; r < 4; ++r) t8[r] = fmaxf(t8[r], t8[r + 4]);
    float tmax = fmaxf(fmaxf(t8[0], t8[1]), fmaxf(t8[2], t8[3]));
    tmax = fmaxf(tmax, __shfl_xor(tmax, 32, 64));
    const float mnew = fmaxf(m, tmax);
    const float scale = __expf(m - mnew);
    m = mnew;
    lsum *= scale;
#pragma unroll
    for (int r = 0; r < 8; ++r) acc[r] *= scale;

    float p[16];
    float psum = 0.f;
#pragma unroll
    for (int r = 0; r < 16; ++r) { p[r] = __expf(s[r] - mnew); psum += p[r]; }
    lsum += psum;

    short8 pa, pb;
#pragma unroll
    for (int j = 0; j < 8; ++j) { pa[j] = f2bfs(p[j]); pb[j] = f2bfs(p[8 + j]); }

    const short* vtr = vtw + (l31 & 15) * 36;
    I4S8 a1, a2;
    a1.h[0] = *(const int2*)(vtr + 4 * g);
    a1.h[1] = *(const int2*)(vtr + 8 + 4 * g);
    a2.h[0] = *(const int2*)(vtr + 16 + 4 * g);
    a2.h[1] = *(const int2*)(vtr + 24 + 4 * g);
    acc = __builtin_amdgcn_mfma_f32_32x32x16_bf16(a1.s, pa, acc, 0, 0, 0);
    acc = __builtin_amdgcn_mfma_f32_32x32x16_bf16(a2.s, pb, acc, 0, 0, 0);
  }

  const float total = lsum + __shfl_xor(lsum, 32, 64);
  const float inv = 1.f / total;
  const int qi = q0 + l31;
  short* dst = ao + ((size_t)qi * BATCH + batch) * CC + hh * 16 + 4 * g;
  uint2 o1, o2;
  o1.x = pack2(acc[0] * inv, acc[1] * inv);
  o1.y = pack2(acc[2] * inv, acc[3] * inv);
  o2.x = pack2(acc[4] * inv, acc[5] * inv);
  o2.y = pack2(acc[6] * inv, acc[7] * inv);
  *(uint2*)dst = o1;
  *(uint2*)(dst + 8) = o2;
}

// ---------------- K3: long out-proj + pos + short QKV proj (MFMA x2) ----------------
__global__ __launch_bounds__(256) void k_mid(
    const short* __restrict__ ao, const short* __restrict__ pos_ct,
    const short* __restrict__ wobf, const float* __restrict__ b_out_l,
    const short* __restrict__ wibf, const float* __restrict__ b_in_s,
    short* __restrict__ qb, short* __restrict__ kb, short* __restrict__ vb) {
  __shared__ short YQK[32][132], YV[32][132];
  const int tid = threadIdx.x;
  const int wid = tid >> 6, lane = tid & 63;
  const int l31 = lane & 31, g = lane >> 5;
  const int tok0 = blockIdx.x * 32;
  const int l = tok0 >> 9, b0 = tok0 & 511;
  const int t = l >> 4, bh = (l >> 2) & 3, bw = l & 3;
  const int nb = b0 >> 8, ph0 = (b0 >> 4) & 15;
  // ---- phase A: y = ao . W_out^T + b ; YQK = y+pos, YV = y (bf16 LDS)
  {
    const int nch = wid * 32 + l31;
    f32x16 acc = fzero16();
#pragma unroll
    for (int k0 = 0; k0 < 128; k0 += 16) {
      short8 af = *(const short8*)(ao + (size_t)(tok0 + l31) * CC + k0 + 8 * g);
      short8 bf = *(const short8*)(wobf + nch * CC + k0 + 8 * g);
      acc = __builtin_amdgcn_mfma_f32_32x32x16_bf16(af, bf, acc, 0, 0, 0);
    }
    const float bias = b_out_l[nch];
    float pos[16];
#pragma unroll
    for (int rr = 0; rr < 4; ++rr) {
      int2 pp = *(const int2*)(pos_ct + (size_t)nch * 32768 + tok0 + rr * 8 + 4 * g);
      pos[rr * 4 + 0] = bflo((unsigned int)pp.x);
      pos[rr * 4 + 1] = bfhi((unsigned int)pp.x);
      pos[rr * 4 + 2] = bflo((unsigned int)pp.y);
      pos[rr * 4 + 3] = bfhi((unsigned int)pp.y);
    }
#pragma unroll
    for (int r = 0; r < 16; ++r) {
      const int tt = (r & 3) + 8 * (r >> 2) + 4 * g;
      const float y = acc[r] + bias;
      YV[tt][nch] = f2bfs(y);
      YQK[tt][nch] = f2bfs(y + pos[r]);
    }
  }
  __syncthreads();
  // ---- phase B: short QKV projection
  const int bs = nb * 16 + bh * 4 + bw;
  const int ls0 = (t * 16 + ph0) * 16;
  for (int i = 0; i < 3; ++i) {
    const int nt = wid + 4 * i;
    const int nch = nt * 32 + l31;          // 0..383
    const int which = nt >> 2;
    const short (*X)[132] = (which == 2) ? YV : YQK;
    f32x16 acc = fzero16();
#pragma unroll
    for (int k0 = 0; k0 < 128; k0 += 16) {
      I4S8 af;
      af.h[0] = *(const int2*)&X[l31][k0 + 8 * g];
      af.h[1] = *(const int2*)&X[l31][k0 + 8 * g + 4];
      short8 bf = *(const short8*)(wibf + nch * CC + k0 + 8 * g);
      acc = __builtin_amdgcn_mfma_f32_32x32x16_bf16(af.s, bf, acc, 0, 0, 0);
    }
    const float bias = b_in_s[nch];
    const float qsc = (which == 0) ? 0.25f : 1.0f;
    const int hh = (nch >> 4) & 7, d = nch & 15;
    short* dst = (which == 0) ? qb : (which == 1) ? kb : vb;
    const size_t base = ((size_t)(bs * 8 + hh) * 1024 + ls0) * 16 + d;
#pragma unroll
    for (int r = 0; r < 16; ++r) {
      const int tt = (r & 3) + 8 * (r >> 2) + 4 * g;
      dst[base + (size_t)tt * 16] = f2bfs((acc[r] + bias) * qsc);
    }
  }
}

// ---------------- K4: short out-proj + scatter to (N,C,T,H,W) fp32, MFMA ----------------
__global__ __launch_bounds__(256) void k_out_short(
    const short* __restrict__ ao, const short* __restrict__ wbf,
    const float* __restrict__ b_out, float* __restrict__ out) {
  const int tid = threadIdx.x;
  const int wid = tid >> 6, lane = tid & 63;
  const int l31 = lane & 31, g = lane >> 5;
  const int bs = blockIdx.x & 31;
  const int qi0 = (blockIdx.x >> 5) << 5;
  const int nb = bs >> 4, bh = (bs >> 2) & 3, bw = bs & 3;
  const int t = qi0 >> 8, ph0 = (qi0 >> 4) & 15;
  const int nch = wid * 32 + l31;
  f32x16 acc = fzero16();
#pragma unroll
  for (int k0 = 0; k0 < 128; k0 += 16) {
    short8 af = *(const short8*)(ao + ((size_t)(qi0 + l31) * 32 + bs) * CC + k0 + 8 * g);
    short8 bf = *(const short8*)(wbf + nch * CC + k0 + 8 * g);
    acc = __builtin_amdgcn_mfma_f32_32x32x16_bf16(af, bf, acc, 0, 0, 0);
  }
  const float bias = b_out[nch];
#pragma unroll
  for (int rr = 0; rr < 4; ++rr) {
    const int tt0 = rr * 8 + 4 * g;               // 4 consecutive tokens
    const int ph_off = tt0 >> 4, pw = tt0 & 15;
    const int h = bh * 16 + ph0 + ph_off, w = bw * 16 + pw;
    const size_t adr = (((size_t)(nb * CC + nch) * 4 + t) << 12) + h * 64 + w;
    float4 f;
    f.x = acc[rr * 4 + 0] + bias; f.y = acc[rr * 4 + 1] + bias;
    f.z = acc[rr * 4 + 2] + bias; f.w = acc[rr * 4 + 3] + bias;
    *(float4*)(out + adr) = f;
  }
}

extern "C" void kernel_launch(void* const* d_in, const int* in_sizes, int n_in,
                              void* d_out, int out_size, void* d_ws, size_t ws_size,
                              hipStream_t stream) {
  (void)in_sizes; (void)n_in; (void)out_size; (void)ws_size;
  const float* q   = (const float*)d_in[0];
  const float* k   = (const float*)d_in[1];
  const float* v   = (const float*)d_in[2];
  const float* pq  = (const float*)d_in[3];
  const float* pk  = (const float*)d_in[4];
  const float* wil = (const float*)d_in[5];
  const float* bil = (const float*)d_in[6];
  const float* wol = (const float*)d_in[7];
  const float* bol = (const float*)d_in[8];
  const float* wis = (const float*)d_in[9];
  const float* bis = (const float*)d_in[10];
  const float* wos = (const float*)d_in[11];
  const float* bos = (const float*)d_in[12];

  short* qs     = (short*)d_ws;            // 4.19M shorts each region
  short* ksb    = qs + 4194304;
  short* vsb    = ksb + 4194304;
  short* ao     = vsb + 4194304;
  short* pos_ct = ao + 4194304;
  short* wbf    = pos_ct + 4194304;        // 131072 shorts

  k_cvtw<<<dim3(64), dim3(256), 0, stream>>>(wil, wol, wis, wos, wbf);
  k_proj_long<<<dim3(1024), dim3(256), 0, stream>>>(q, k, v, pq, pk, wbf, bil,
                                                    qs, ksb, vsb, pos_ct);
  k_attn<64, 512><<<dim3(2048), dim3(256), 0, stream>>>(qs, ksb, vsb, ao);
  k_mid<<<dim3(1024), dim3(256), 0, stream>>>(ao, pos_ct, wbf + 49152, bol,
                                              wbf + 65536, bis, qs, ksb, vsb);
  k_attn<1024, 32><<<dim3(2048), dim3(256), 0, stream>>>(qs, ksb, vsb, ao);
  k_out_short<<<dim3(1024), dim3(256), 0, stream>>>(ao, wbf + 114688, bos,
                                                    (float*)d_out);
}